// Round 1
// baseline (26.677 us; speedup 1.0000x reference)
//
#include <hip/hip_runtime.h>
#include <hip/hip_bf16.h>
#include <math.h>

#define H 32
#define MAXNBR 2048

// ---------------- Kernel 1: h_all = z @ W_h_w.T + W_h_b  [N,H] ----------------
__global__ __launch_bounds__(256) void hall_kernel(
    const float* __restrict__ z, const float* __restrict__ W_h_w,
    const float* __restrict__ W_h_b, float* __restrict__ h_all, int total)
{
    __shared__ float Wsh[H * H];
    __shared__ float Bsh[H];
    int tid = threadIdx.x;
    for (int i = tid; i < H * H; i += 256) Wsh[i] = W_h_w[i];
    if (tid < H) Bsh[tid] = W_h_b[tid];
    __syncthreads();
    int idx = blockIdx.x * 256 + tid;
    if (idx >= total) return;
    int n = idx >> 5;          // node
    int h = idx & 31;          // feature
    const float* zr = z + (size_t)n * H;
    float acc = Bsh[h];
#pragma unroll
    for (int j = 0; j < H; j++) acc += Wsh[h * H + j] * zr[j];
    h_all[idx] = acc;
}

// ---------------- Kernel 2: per-(b,j) struct aggregation + z_new ----------------
__global__ __launch_bounds__(256) void struct_kernel(
    const float* __restrict__ S,          // [N,N]
    const float* __restrict__ z,          // [N,H]
    const float* __restrict__ h_all,      // [N,H]
    const int* __restrict__ u_idx, const int* __restrict__ v_idx,
    const float* __restrict__ time_delta, // [B,2,4]
    const float* __restrict__ W_struct_w, const float* __restrict__ W_struct_b,
    const float* __restrict__ W_rec_w, const float* __restrict__ W_rec_b,
    const float* __restrict__ W_t_w, const float* __restrict__ W_t_b,
    float* __restrict__ out_znew,         // d_out + B, [B,2,H]
    int N)
{
    int pair = blockIdx.x;               // b*2 + j
    int b = pair >> 1;
    int j = pair & 1;
    int target  = (j == 0) ? u_idx[b] : v_idx[b];
    int partner = (j == 0) ? v_idx[b] : u_idx[b];

    __shared__ int   s_cnt;
    __shared__ float s_red[256];
    __shared__ int   s_nbr[MAXNBR];
    __shared__ float s_eq[MAXNBR];       // exp(S[partner, n]) for neighbors
    __shared__ float s_max[8][H];
    __shared__ float s_hstruct[H];

    int tid = threadIdx.x;
    if (tid == 0) s_cnt = 0;
    __syncthreads();

    // Pass 1: scan row S[partner], collect neighbors (S>0 <=> A>0), accumulate exp-sum
    const float* Srow = S + (size_t)partner * N;
    float psum = 0.f;
    for (int n = tid; n < N; n += 256) {
        float sv = Srow[n];
        if (sv > 0.f) {
            float e = expf(sv);
            int pos = atomicAdd(&s_cnt, 1);
            if (pos < MAXNBR) { s_nbr[pos] = n; s_eq[pos] = e; }
            psum += e;
        }
    }
    s_red[tid] = psum;
    __syncthreads();
    for (int s = 128; s > 0; s >>= 1) {
        if (tid < s) s_red[tid] += s_red[tid + s];
        __syncthreads();
    }
    float qsum = s_red[0] + 1e-7f;
    int cnt = s_cnt;
    if (cnt > MAXNBR) cnt = MAXNBR;

    // Pass 2: h_struct[h] = max over neighbors of sigmoid(q_n * h_all[n,h])
    int grp = tid >> 5;   // 0..7 neighbor group
    int h   = tid & 31;   // feature lane
    float m = -INFINITY;
    for (int i = grp; i < cnt; i += 8) {
        float q = s_eq[i] / qsum;
        float val = h_all[(size_t)s_nbr[i] * H + h];
        float sg = 1.f / (1.f + expf(-q * val));
        m = fmaxf(m, sg);
    }
    s_max[grp][h] = m;
    __syncthreads();
    if (tid < H) {
        float mm = s_max[0][tid];
#pragma unroll
        for (int g = 1; g < 8; g++) mm = fmaxf(mm, s_max[g][tid]);
        s_hstruct[tid] = (cnt > 0) ? mm : 0.f;
    }
    __syncthreads();

    // Epilogue: z_new = sigmoid(W_struct(h_struct) + W_rec(z[target]) + W_t(td))
    if (tid < H) {
        int hh = tid;
        float acc = W_struct_b[hh] + W_rec_b[hh] + W_t_b[hh];
        const float* zt = z + (size_t)target * H;
#pragma unroll
        for (int jj = 0; jj < H; jj++) {
            acc += W_struct_w[hh * H + jj] * s_hstruct[jj];
            acc += W_rec_w[hh * H + jj] * zt[jj];
        }
        const float* td = time_delta + (size_t)pair * 4;
#pragma unroll
        for (int jj = 0; jj < 4; jj++) acc += W_t_w[hh * 4 + jj] * td[jj];
        out_znew[(size_t)pair * H + hh] = 1.f / (1.f + expf(-acc));
    }
}

// ---------------- Kernel 3: Lambda ----------------
__global__ __launch_bounds__(256) void lambda_kernel(
    const float* __restrict__ z,
    const int* __restrict__ u_idx, const int* __restrict__ v_idx,
    const int* __restrict__ k,
    const float* __restrict__ om0_w, const float* __restrict__ om0_b,
    const float* __restrict__ om1_w, const float* __restrict__ om1_b,
    const float* __restrict__ psi,
    float* __restrict__ out_lambda, int B)
{
    int b = blockIdx.x * 256 + threadIdx.x;
    if (b >= B) return;
    bool kpos = k[b] > 0;
    const float* om_w = kpos ? om1_w : om0_w;
    float om_bias = kpos ? om1_b[0] : om0_b[0];
    const float* zu = z + (size_t)u_idx[b] * H;
    const float* zv = z + (size_t)v_idx[b] * H;
    // g = 0.5*(g(cat_uv)+g(cat_vu)) = 0.5 * sum_h (w[h]+w[h+H])*(zu[h]+zv[h]) + bias
    float g = 0.f;
#pragma unroll
    for (int hh = 0; hh < H; hh++)
        g += (om_w[hh] + om_w[hh + H]) * (zu[hh] + zv[hh]);
    g = 0.5f * g + om_bias;
    float psi_k = psi[kpos ? 1 : 0];
    float gp = g / (psi_k + 1e-7f);
    gp = fminf(fmaxf(gp, -75.f), 75.f);
    out_lambda[b] = psi_k * (log1pf(expf(-gp)) + gp);
}

extern "C" void kernel_launch(void* const* d_in, const int* in_sizes, int n_in,
                              void* d_out, int out_size, void* d_ws, size_t ws_size,
                              hipStream_t stream) {
    const float* z          = (const float*)d_in[0];
    // d_in[1] = A  (unused: A>0 <=> S>0)
    const float* S          = (const float*)d_in[2];
    const int*   u_idx      = (const int*)d_in[3];
    const int*   v_idx      = (const int*)d_in[4];
    const int*   k          = (const int*)d_in[5];
    const float* time_delta = (const float*)d_in[6];
    const float* W_h_w      = (const float*)d_in[7];
    const float* W_h_b      = (const float*)d_in[8];
    const float* W_struct_w = (const float*)d_in[9];
    const float* W_struct_b = (const float*)d_in[10];
    const float* W_rec_w    = (const float*)d_in[11];
    const float* W_rec_b    = (const float*)d_in[12];
    const float* W_t_w      = (const float*)d_in[13];
    const float* W_t_b      = (const float*)d_in[14];
    const float* om0_w      = (const float*)d_in[15];
    const float* om0_b      = (const float*)d_in[16];
    const float* om1_w      = (const float*)d_in[17];
    const float* om1_b      = (const float*)d_in[18];
    const float* psi        = (const float*)d_in[19];

    const int B = in_sizes[3];           // 256
    const int N = in_sizes[0] / H;       // 8192
    float* out        = (float*)d_out;
    float* out_lambda = out;             // [B]
    float* out_znew   = out + B;         // [B,2,H]
    float* h_all      = (float*)d_ws;    // [N,H] = 1 MB

    int total = N * H;
    hall_kernel<<<(total + 255) / 256, 256, 0, stream>>>(z, W_h_w, W_h_b, h_all, total);
    lambda_kernel<<<(B + 255) / 256, 256, 0, stream>>>(
        z, u_idx, v_idx, k, om0_w, om0_b, om1_w, om1_b, psi, out_lambda, B);
    struct_kernel<<<B * 2, 256, 0, stream>>>(
        S, z, h_all, u_idx, v_idx, time_delta,
        W_struct_w, W_struct_b, W_rec_w, W_rec_b, W_t_w, W_t_b,
        out_znew, N);
}

// Round 2
// 15.498 us; speedup vs baseline: 1.7214x; 1.7214x over previous
//
#include <hip/hip_runtime.h>
#include <hip/hip_bf16.h>
#include <math.h>

#define H 32
#define MAXNBR 512
#define CHUNK 64

// One block per (b, j) pair: scans S[partner], builds attention q over
// neighbors, computes h_all on the fly for just the neighbors, max-pools
// sigmoid(q*h), then the z_new epilogue. j==0 blocks also compute Lambda[b].
__global__ __launch_bounds__(256) void fused_kernel(
    const float* __restrict__ S,          // [N,N]
    const float* __restrict__ z,          // [N,H]
    const int* __restrict__ u_idx, const int* __restrict__ v_idx,
    const int* __restrict__ k,
    const float* __restrict__ time_delta, // [B,2,4]
    const float* __restrict__ W_h_w, const float* __restrict__ W_h_b,
    const float* __restrict__ W_struct_w, const float* __restrict__ W_struct_b,
    const float* __restrict__ W_rec_w, const float* __restrict__ W_rec_b,
    const float* __restrict__ W_t_w, const float* __restrict__ W_t_b,
    const float* __restrict__ om0_w, const float* __restrict__ om0_b,
    const float* __restrict__ om1_w, const float* __restrict__ om1_b,
    const float* __restrict__ psi,
    float* __restrict__ out_lambda,       // [B]
    float* __restrict__ out_znew,         // [B,2,H]
    int N)
{
    int pair = blockIdx.x;               // b*2 + j
    int b = pair >> 1;
    int j = pair & 1;
    int u = u_idx[b], v = v_idx[b];
    int target  = (j == 0) ? u : v;
    int partner = (j == 0) ? v : u;

    __shared__ float WshT[H * H];        // W_h_w transposed: WshT[j*H+h]
    __shared__ float Bsh[H];
    __shared__ int   s_cnt;
    __shared__ float s_red[256];
    __shared__ int   s_nbr[MAXNBR];
    __shared__ float s_eq[MAXNBR];
    __shared__ float zsh[CHUNK][H];
    __shared__ float s_max[8][H];
    __shared__ float s_hstruct[H];

    int tid = threadIdx.x;
    if (tid == 0) s_cnt = 0;
    // stage W_h transposed (conflict-free reads later: lanes h consecutive)
    for (int i = tid; i < H * H; i += 256) {
        int hh = i >> 5, jj = i & 31;
        WshT[jj * H + hh] = W_h_w[i];
    }
    if (tid < H) Bsh[tid] = W_h_b[tid];

    // Lambda for this b (only j==0 block; independent of shared state above
    // except it must not race the __syncthreads pattern -> done by one thread
    // before first sync, it only reads globals)
    if (j == 0 && tid == 255) {
        bool kpos = k[b] > 0;
        const float* om_w = kpos ? om1_w : om0_w;
        float om_bias = kpos ? om1_b[0] : om0_b[0];
        const float* zu = z + (size_t)u * H;
        const float* zv = z + (size_t)v * H;
        float g = 0.f;
#pragma unroll
        for (int hh = 0; hh < H; hh++)
            g += (om_w[hh] + om_w[hh + H]) * (zu[hh] + zv[hh]);
        g = 0.5f * g + om_bias;
        float psi_k = psi[kpos ? 1 : 0];
        float gp = g / (psi_k + 1e-7f);
        gp = fminf(fmaxf(gp, -75.f), 75.f);
        out_lambda[b] = psi_k * (log1pf(expf(-gp)) + gp);
    }
    __syncthreads();

    // Pass 1: float4 scan of S[partner]; collect neighbors + exp-sum
    const float4* Srow4 = (const float4*)(S + (size_t)partner * N);
    float psum = 0.f;
    int n4 = N >> 2;
    for (int it = tid; it < n4; it += 256) {
        float4 sv = Srow4[it];
        const float* svp = &sv.x;
#pragma unroll
        for (int c = 0; c < 4; c++) {
            float s = svp[c];
            if (s > 0.f) {
                float e = expf(s);
                int pos = atomicAdd(&s_cnt, 1);
                if (pos < MAXNBR) { s_nbr[pos] = it * 4 + c; s_eq[pos] = e; }
                psum += e;
            }
        }
    }
    s_red[tid] = psum;
    __syncthreads();
    for (int s = 128; s > 0; s >>= 1) {
        if (tid < s) s_red[tid] += s_red[tid + s];
        __syncthreads();
    }
    float inv_qsum = 1.f / (s_red[0] + 1e-7f);
    int cnt = s_cnt;
    if (cnt > MAXNBR) cnt = MAXNBR;

    // Pass 2: chunked z staging + on-the-fly h + sigmoid max-pool
    int grp = tid >> 5;   // neighbor group 0..7
    int h   = tid & 31;   // feature lane
    float mmax = -INFINITY;
    for (int base = 0; base < cnt; base += CHUNK) {
        int m = min(CHUNK, cnt - base);
        // stage m z-rows: 8 threads per row, float4 each
        for (int t = tid; t < m * 8; t += 256) {
            int i = t >> 3, c = t & 7;
            ((float4*)zsh[i])[c] =
                ((const float4*)(z + (size_t)s_nbr[base + i] * H))[c];
        }
        __syncthreads();
        for (int i = grp; i < m; i += 8) {
            float q = s_eq[base + i] * inv_qsum;
            float hv = Bsh[h];
#pragma unroll
            for (int jj = 0; jj < H; jj++)
                hv += WshT[jj * H + h] * zsh[i][jj];
            float sg = 1.f / (1.f + expf(-q * hv));
            mmax = fmaxf(mmax, sg);
        }
        __syncthreads();
    }
    s_max[grp][h] = mmax;
    __syncthreads();
    if (tid < H) {
        float mm = s_max[0][tid];
#pragma unroll
        for (int g = 1; g < 8; g++) mm = fmaxf(mm, s_max[g][tid]);
        s_hstruct[tid] = (cnt > 0) ? mm : 0.f;
    }
    __syncthreads();

    // Epilogue: z_new = sigmoid(W_struct(h_struct) + W_rec(z[target]) + W_t(td))
    if (tid < H) {
        int hh = tid;
        float acc = W_struct_b[hh] + W_rec_b[hh] + W_t_b[hh];
        const float* zt = z + (size_t)target * H;
#pragma unroll
        for (int jj = 0; jj < H; jj++) {
            acc += W_struct_w[hh * H + jj] * s_hstruct[jj];
            acc += W_rec_w[hh * H + jj] * zt[jj];
        }
        const float* td = time_delta + (size_t)pair * 4;
#pragma unroll
        for (int jj = 0; jj < 4; jj++) acc += W_t_w[hh * 4 + jj] * td[jj];
        out_znew[(size_t)pair * H + hh] = 1.f / (1.f + expf(-acc));
    }
}

extern "C" void kernel_launch(void* const* d_in, const int* in_sizes, int n_in,
                              void* d_out, int out_size, void* d_ws, size_t ws_size,
                              hipStream_t stream) {
    const float* z          = (const float*)d_in[0];
    // d_in[1] = A  (unused: A>0 <=> S>0)
    const float* S          = (const float*)d_in[2];
    const int*   u_idx      = (const int*)d_in[3];
    const int*   v_idx      = (const int*)d_in[4];
    const int*   k          = (const int*)d_in[5];
    const float* time_delta = (const float*)d_in[6];
    const float* W_h_w      = (const float*)d_in[7];
    const float* W_h_b      = (const float*)d_in[8];
    const float* W_struct_w = (const float*)d_in[9];
    const float* W_struct_b = (const float*)d_in[10];
    const float* W_rec_w    = (const float*)d_in[11];
    const float* W_rec_b    = (const float*)d_in[12];
    const float* W_t_w      = (const float*)d_in[13];
    const float* W_t_b      = (const float*)d_in[14];
    const float* om0_w      = (const float*)d_in[15];
    const float* om0_b      = (const float*)d_in[16];
    const float* om1_w      = (const float*)d_in[17];
    const float* om1_b      = (const float*)d_in[18];
    const float* psi        = (const float*)d_in[19];

    const int B = in_sizes[3];           // 256
    const int N = in_sizes[0] / H;       // 8192
    float* out        = (float*)d_out;
    float* out_lambda = out;             // [B]
    float* out_znew   = out + B;         // [B,2,H]

    fused_kernel<<<B * 2, 256, 0, stream>>>(
        S, z, u_idx, v_idx, k, time_delta,
        W_h_w, W_h_b, W_struct_w, W_struct_b, W_rec_w, W_rec_b, W_t_w, W_t_b,
        om0_w, om0_b, om1_w, om1_b, psi,
        out_lambda, out_znew, N);
}

// Round 3
// 14.334 us; speedup vs baseline: 1.8611x; 1.0812x over previous
//
#include <hip/hip_runtime.h>
#include <hip/hip_bf16.h>
#include <math.h>

#define H 32
#define MAXNBR 512
#define CHUNK 64

// One block per (b, j) pair. Latency-optimized:
//  - all 8 float4 S-row loads issued up front (N==8192 fast path)
//  - W_h staging + Lambda hide under the S-row HBM latency
//  - wave-level shfl reduction (1 __syncthreads instead of 8)
__global__ __launch_bounds__(256) void fused_kernel(
    const float* __restrict__ S,          // [N,N]
    const float* __restrict__ z,          // [N,H]
    const int* __restrict__ u_idx, const int* __restrict__ v_idx,
    const int* __restrict__ k,
    const float* __restrict__ time_delta, // [B,2,4]
    const float* __restrict__ W_h_w, const float* __restrict__ W_h_b,
    const float* __restrict__ W_struct_w, const float* __restrict__ W_struct_b,
    const float* __restrict__ W_rec_w, const float* __restrict__ W_rec_b,
    const float* __restrict__ W_t_w, const float* __restrict__ W_t_b,
    const float* __restrict__ om0_w, const float* __restrict__ om0_b,
    const float* __restrict__ om1_w, const float* __restrict__ om1_b,
    const float* __restrict__ psi,
    float* __restrict__ out_lambda,       // [B]
    float* __restrict__ out_znew,         // [B,2,H]
    int N)
{
    int pair = blockIdx.x;               // b*2 + j
    int b = pair >> 1;
    int j = pair & 1;
    int u = u_idx[b], v = v_idx[b];
    int target  = (j == 0) ? u : v;
    int partner = (j == 0) ? v : u;

    __shared__ float WshT[H * H];        // W_h_w transposed: WshT[j*H+h]
    __shared__ float Bsh[H];
    __shared__ int   s_cnt;
    __shared__ float s_wred[4];
    __shared__ int   s_nbr[MAXNBR];
    __shared__ float s_eq[MAXNBR];
    __shared__ float zsh[CHUNK][H];
    __shared__ float s_max[8][H];
    __shared__ float s_hstruct[H];

    int tid = threadIdx.x;
    if (tid == 0) s_cnt = 0;

    // ---- issue the big S-row fetch FIRST (independent HBM loads) ----
    const float4* Srow4 = (const float4*)(S + (size_t)partner * N);
    int n4 = N >> 2;
    bool fast = (n4 == 2048);
    float4 sv[8];
    if (fast) {
#pragma unroll
        for (int r = 0; r < 8; r++) sv[r] = Srow4[tid + r * 256];
    }

    // ---- these hide under the S-row latency ----
    for (int i = tid; i < H * H; i += 256) {
        int hh = i >> 5, jj = i & 31;
        WshT[jj * H + hh] = W_h_w[i];
    }
    if (tid < H) Bsh[tid] = W_h_b[tid];

    if (j == 0 && tid == 255) {          // Lambda[b], reads globals only
        bool kpos = k[b] > 0;
        const float* om_w = kpos ? om1_w : om0_w;
        float om_bias = kpos ? om1_b[0] : om0_b[0];
        const float* zu = z + (size_t)u * H;
        const float* zv = z + (size_t)v * H;
        float g = 0.f;
#pragma unroll
        for (int hh = 0; hh < H; hh++)
            g += (om_w[hh] + om_w[hh + H]) * (zu[hh] + zv[hh]);
        g = 0.5f * g + om_bias;
        float psi_k = psi[kpos ? 1 : 0];
        float gp = g / (psi_k + 1e-7f);
        gp = fminf(fmaxf(gp, -75.f), 75.f);
        out_lambda[b] = psi_k * (log1pf(expf(-gp)) + gp);
    }
    __syncthreads();                     // s_cnt init + WshT/Bsh visible

    // ---- pass 1: process S values from registers ----
    float psum = 0.f;
    if (fast) {
#pragma unroll
        for (int r = 0; r < 8; r++) {
            const float* svp = (const float*)&sv[r];
#pragma unroll
            for (int c = 0; c < 4; c++) {
                float s = svp[c];
                if (s > 0.f) {
                    float e = expf(s);
                    int pos = atomicAdd(&s_cnt, 1);
                    if (pos < MAXNBR) {
                        s_nbr[pos] = (tid + r * 256) * 4 + c;
                        s_eq[pos] = e;
                    }
                    psum += e;
                }
            }
        }
    } else {
        for (int it = tid; it < n4; it += 256) {
            float4 s4 = Srow4[it];
            const float* svp = (const float*)&s4;
#pragma unroll
            for (int c = 0; c < 4; c++) {
                float s = svp[c];
                if (s > 0.f) {
                    float e = expf(s);
                    int pos = atomicAdd(&s_cnt, 1);
                    if (pos < MAXNBR) { s_nbr[pos] = it * 4 + c; s_eq[pos] = e; }
                    psum += e;
                }
            }
        }
    }
    // wave-level reduce (64 lanes), then 4 partials in LDS
#pragma unroll
    for (int off = 32; off > 0; off >>= 1) psum += __shfl_xor(psum, off);
    if ((tid & 63) == 0) s_wred[tid >> 6] = psum;
    __syncthreads();                     // partials + s_cnt + s_nbr/s_eq ready
    float inv_qsum = 1.f / (s_wred[0] + s_wred[1] + s_wred[2] + s_wred[3] + 1e-7f);
    int cnt = s_cnt;
    if (cnt > MAXNBR) cnt = MAXNBR;

    // ---- pass 2: chunked z staging + on-the-fly h + sigmoid max-pool ----
    int grp = tid >> 5;   // neighbor group 0..7
    int h   = tid & 31;   // feature lane
    float mmax = -INFINITY;
    for (int base = 0; base < cnt; base += CHUNK) {
        int m = min(CHUNK, cnt - base);
        for (int t = tid; t < m * 8; t += 256) {
            int i = t >> 3, c = t & 7;
            ((float4*)zsh[i])[c] =
                ((const float4*)(z + (size_t)s_nbr[base + i] * H))[c];
        }
        __syncthreads();
        for (int i = grp; i < m; i += 8) {
            float q = s_eq[base + i] * inv_qsum;
            float hv = Bsh[h];
#pragma unroll
            for (int jj = 0; jj < H; jj++)
                hv += WshT[jj * H + h] * zsh[i][jj];
            float sg = 1.f / (1.f + expf(-q * hv));
            mmax = fmaxf(mmax, sg);
        }
        __syncthreads();
    }
    s_max[grp][h] = mmax;
    __syncthreads();
    if (tid < H) {
        float mm = s_max[0][tid];
#pragma unroll
        for (int g = 1; g < 8; g++) mm = fmaxf(mm, s_max[g][tid]);
        s_hstruct[tid] = (cnt > 0) ? mm : 0.f;
    }
    __syncthreads();

    // ---- epilogue ----
    if (tid < H) {
        int hh = tid;
        float acc = W_struct_b[hh] + W_rec_b[hh] + W_t_b[hh];
        const float* zt = z + (size_t)target * H;
#pragma unroll
        for (int jj = 0; jj < H; jj++) {
            acc += W_struct_w[hh * H + jj] * s_hstruct[jj];
            acc += W_rec_w[hh * H + jj] * zt[jj];
        }
        const float* td = time_delta + (size_t)pair * 4;
#pragma unroll
        for (int jj = 0; jj < 4; jj++) acc += W_t_w[hh * 4 + jj] * td[jj];
        out_znew[(size_t)pair * H + hh] = 1.f / (1.f + expf(-acc));
    }
}

extern "C" void kernel_launch(void* const* d_in, const int* in_sizes, int n_in,
                              void* d_out, int out_size, void* d_ws, size_t ws_size,
                              hipStream_t stream) {
    const float* z          = (const float*)d_in[0];
    // d_in[1] = A  (unused: A>0 <=> S>0)
    const float* S          = (const float*)d_in[2];
    const int*   u_idx      = (const int*)d_in[3];
    const int*   v_idx      = (const int*)d_in[4];
    const int*   k          = (const int*)d_in[5];
    const float* time_delta = (const float*)d_in[6];
    const float* W_h_w      = (const float*)d_in[7];
    const float* W_h_b      = (const float*)d_in[8];
    const float* W_struct_w = (const float*)d_in[9];
    const float* W_struct_b = (const float*)d_in[10];
    const float* W_rec_w    = (const float*)d_in[11];
    const float* W_rec_b    = (const float*)d_in[12];
    const float* W_t_w      = (const float*)d_in[13];
    const float* W_t_b      = (const float*)d_in[14];
    const float* om0_w      = (const float*)d_in[15];
    const float* om0_b      = (const float*)d_in[16];
    const float* om1_w      = (const float*)d_in[17];
    const float* om1_b      = (const float*)d_in[18];
    const float* psi        = (const float*)d_in[19];

    const int B = in_sizes[3];           // 256
    const int N = in_sizes[0] / H;       // 8192
    float* out        = (float*)d_out;
    float* out_lambda = out;             // [B]
    float* out_znew   = out + B;         // [B,2,H]

    fused_kernel<<<B * 2, 256, 0, stream>>>(
        S, z, u_idx, v_idx, k, time_delta,
        W_h_w, W_h_b, W_struct_w, W_struct_b, W_rec_w, W_rec_b, W_t_w, W_t_b,
        om0_w, om0_b, om1_w, om1_b, psi,
        out_lambda, out_znew, N);
}